// Round 1
// baseline (3771.290 us; speedup 1.0000x reference)
//
#include <hip/hip_runtime.h>

#define NN 100000
#define NE 1600000
#define CH 64
#define STEPS 10
#define ALPHA 0.1f

// ---- degree count: one thread per edge, atomic add to deg[dst] ----
__global__ void k_deg(const int* __restrict__ dst, float* __restrict__ deg, int E) {
    int e = blockIdx.x * blockDim.x + threadIdx.x;
    if (e < E) atomicAdd(&deg[dst[e]], 1.0f);
}

// ---- dinv = rsqrt(max(deg,1)) in place ----
__global__ void k_dinv(float* __restrict__ deg, int n) {
    int i = blockIdx.x * blockDim.x + threadIdx.x;
    if (i < n) deg[i] = rsqrtf(fmaxf(deg[i], 1.0f));
}

// ---- per-edge norm = dinv[src]*dinv[dst] ----
__global__ void k_norm(const int* __restrict__ src, const int* __restrict__ dst,
                       const float* __restrict__ dinv, float* __restrict__ norm, int E) {
    int e = blockIdx.x * blockDim.x + threadIdx.x;
    if (e < E) norm[e] = dinv[src[e]] * dinv[dst[e]];
}

// ---- propagation: thread = (edge, channel); 64 lanes cover one edge row ----
__global__ void k_scatter(const int* __restrict__ src, const int* __restrict__ dst,
                          const float* __restrict__ norm,
                          const float* __restrict__ h, float* __restrict__ hn, int E) {
    long long t = (long long)blockIdx.x * blockDim.x + threadIdx.x;
    int e = (int)(t >> 6);
    int c = (int)(t & 63);
    if (e < E) {
        int s = src[e];
        int d = dst[e];
        float v = h[(long long)s * CH + c] * norm[e];
        atomicAdd(&hn[(long long)d * CH + c], v);
    }
}

// ---- acc += hn ----
__global__ void k_accadd(const float* __restrict__ hn, float* __restrict__ acc, int n) {
    int i = blockIdx.x * blockDim.x + threadIdx.x;
    if (i < n) acc[i] += hn[i];
}

// ---- out = alpha*x + (1-alpha)*acc/STEPS ----
__global__ void k_combine(const float* __restrict__ x, const float* __restrict__ acc,
                          float* __restrict__ out, int n) {
    int i = blockIdx.x * blockDim.x + threadIdx.x;
    if (i < n) out[i] = ALPHA * x[i] + (1.0f - ALPHA) * (acc[i] * (1.0f / STEPS));
}

extern "C" void kernel_launch(void* const* d_in, const int* in_sizes, int n_in,
                              void* d_out, int out_size, void* d_ws, size_t ws_size,
                              hipStream_t stream) {
    const float* x  = (const float*)d_in[0];
    const int*   ei = (const int*)d_in[1];      // [2, NE] row-major: row0=src, row1=dst
    const int*   src = ei;
    const int*   dst = ei + NE;
    float* out = (float*)d_out;

    char* ws = (char*)d_ws;
    float* deg  = (float*)(ws);                          // 400 KB
    float* norm = (float*)(ws + (size_t)1  * 1024*1024); // 6.4 MB
    float* hA   = (float*)(ws + (size_t)8  * 1024*1024); // 25.6 MB
    float* hB   = (float*)(ws + (size_t)34 * 1024*1024); // 25.6 MB
    float* acc  = (float*)(ws + (size_t)60 * 1024*1024); // 25.6 MB  (total ~85.6 MB)

    const int NC = NN * CH;

    hipMemsetAsync(deg, 0, NN * sizeof(float), stream);
    hipMemsetAsync(acc, 0, (size_t)NC * sizeof(float), stream);

    k_deg <<<(NE + 255) / 256, 256, 0, stream>>>(dst, deg, NE);
    k_dinv<<<(NN + 255) / 256, 256, 0, stream>>>(deg, NN);
    k_norm<<<(NE + 255) / 256, 256, 0, stream>>>(src, dst, deg, norm, NE);

    const float* hcur = x;
    float* bufs[2] = {hA, hB};
    const long long totalEC = (long long)NE * CH;          // 102.4M threads
    const int scatterBlocks = (int)((totalEC + 255) / 256);

    for (int t = 0; t < STEPS; ++t) {
        float* hn = bufs[t & 1];
        hipMemsetAsync(hn, 0, (size_t)NC * sizeof(float), stream);
        k_scatter<<<scatterBlocks, 256, 0, stream>>>(src, dst, norm, hcur, hn, NE);
        k_accadd<<<(NC + 255) / 256, 256, 0, stream>>>(hn, acc, NC);
        hcur = hn;
    }

    k_combine<<<(NC + 255) / 256, 256, 0, stream>>>(x, acc, out, NC);
}

// Round 2
// 1860.239 us; speedup vs baseline: 2.0273x; 2.0273x over previous
//
#include <hip/hip_runtime.h>

#define NN 100000
#define NE 1600000
#define CH 64
#define STEPS 10
#define ALPHA 0.1f

// ---- histogram of dst ----
__global__ void k_count(const int* __restrict__ dst, int* __restrict__ cnt, int E) {
    int e = blockIdx.x * blockDim.x + threadIdx.x;
    if (e < E) atomicAdd(&cnt[dst[e]], 1);
}

// ---- dinv = rsqrt(max(deg,1)) ----
__global__ void k_dinv(const int* __restrict__ cnt, float* __restrict__ dinv, int n) {
    int i = blockIdx.x * blockDim.x + threadIdx.x;
    if (i < n) dinv[i] = rsqrtf(fmaxf((float)cnt[i], 1.0f));
}

// ---- single-workgroup sequential chunked exclusive scan (100K ints) ----
__global__ void k_scan(const int* __restrict__ cnt, int* __restrict__ rowptr,
                       int* __restrict__ cursor, int n) {
    __shared__ int lds[1024];
    __shared__ int running;
    int tid = threadIdx.x;
    if (tid == 0) running = 0;
    __syncthreads();
    for (int base = 0; base < n; base += 1024) {
        int i = base + tid;
        int v = (i < n) ? cnt[i] : 0;
        lds[tid] = v;
        __syncthreads();
        for (int off = 1; off < 1024; off <<= 1) {
            int t = (tid >= off) ? lds[tid - off] : 0;
            __syncthreads();
            lds[tid] += t;
            __syncthreads();
        }
        int excl = lds[tid] - v;   // exclusive scan within chunk
        int r = running;
        __syncthreads();
        if (i < n) { rowptr[i] = r + excl; cursor[i] = r + excl; }
        if (tid == 1023) running = r + lds[1023];
        __syncthreads();
    }
    if (tid == 0) rowptr[n] = running;
}

// ---- scatter edges into CSR order (by dst), precompute weight ----
__global__ void k_fill(const int* __restrict__ src, const int* __restrict__ dst,
                       const float* __restrict__ dinv, int* __restrict__ cursor,
                       int* __restrict__ col, float* __restrict__ w, int E) {
    int e = blockIdx.x * blockDim.x + threadIdx.x;
    if (e < E) {
        int s = src[e], d = dst[e];
        int pos = atomicAdd(&cursor[d], 1);
        col[pos] = s;
        w[pos] = dinv[s] * dinv[d];
    }
}

// ---- propagation: one wave per destination node, lane = channel ----
template<bool INIT, bool WRITEHN>
__global__ void k_prop(const int* __restrict__ rowptr, const int* __restrict__ col,
                       const float* __restrict__ w, const float* __restrict__ h,
                       float* __restrict__ hn, float* __restrict__ acc) {
    int wid  = (int)((blockIdx.x * (long long)blockDim.x + threadIdx.x) >> 6);
    int lane = threadIdx.x & 63;
    if (wid >= NN) return;
    int start = rowptr[wid];
    int end   = rowptr[wid + 1];
    float a = 0.0f;
    for (int p = start; p < end; ++p) {
        int   s  = col[p];                      // uniform across wave
        float wt = w[p];
        a = fmaf(h[(long long)s * CH + lane], wt, a);
    }
    long long o = (long long)wid * CH + lane;
    if (WRITEHN) hn[o] = a;
    if (INIT) acc[o] = a;
    else      acc[o] += a;
}

// ---- out = alpha*x + (1-alpha)*acc/STEPS, acc lives in out ----
__global__ void k_combine(const float* __restrict__ x, float* __restrict__ acc_out, int n) {
    int i = blockIdx.x * blockDim.x + threadIdx.x;
    if (i < n) acc_out[i] = ALPHA * x[i] + (1.0f - ALPHA) * (acc_out[i] * (1.0f / STEPS));
}

extern "C" void kernel_launch(void* const* d_in, const int* in_sizes, int n_in,
                              void* d_out, int out_size, void* d_ws, size_t ws_size,
                              hipStream_t stream) {
    const float* x  = (const float*)d_in[0];
    const int*   ei = (const int*)d_in[1];     // [2, NE]: row0=src, row1=dst
    const int*   src = ei;
    const int*   dst = ei + NE;
    float* out = (float*)d_out;                // doubles as acc

    char* ws = (char*)d_ws;
    const size_t MB = 1024 * 1024;
    int*   cnt    = (int*)  (ws);                 // 400 KB
    float* dinv   = (float*)(ws + 1 * MB);        // 400 KB
    int*   rowptr = (int*)  (ws + 2 * MB);        // 400 KB (+1)
    int*   cursor = (int*)  (ws + 3 * MB);        // 400 KB
    int*   col    = (int*)  (ws + 4 * MB);        // 6.4 MB
    float* w      = (float*)(ws + 11 * MB);       // 6.4 MB
    float* hA     = (float*)(ws + 18 * MB);       // 25.6 MB
    float* hB     = (float*)(ws + 44 * MB);       // 25.6 MB  (total ~70 MB)

    const int NC = NN * CH;

    hipMemsetAsync(cnt, 0, NN * sizeof(int), stream);
    k_count<<<(NE + 255) / 256, 256, 0, stream>>>(dst, cnt, NE);
    k_dinv <<<(NN + 255) / 256, 256, 0, stream>>>(cnt, dinv, NN);
    k_scan <<<1, 1024, 0, stream>>>(cnt, rowptr, cursor, NN);
    k_fill <<<(NE + 255) / 256, 256, 0, stream>>>(src, dst, dinv, cursor, col, w, NE);

    const int propBlocks = (NN * 64 + 255) / 256;   // one wave per node
    float* bufs[2] = {hA, hB};
    const float* hcur = x;
    for (int t = 0; t < STEPS; ++t) {
        float* hn = bufs[t & 1];
        if (t == 0)
            k_prop<true,  true ><<<propBlocks, 256, 0, stream>>>(rowptr, col, w, hcur, hn, out);
        else if (t == STEPS - 1)
            k_prop<false, false><<<propBlocks, 256, 0, stream>>>(rowptr, col, w, hcur, hn, out);
        else
            k_prop<false, true ><<<propBlocks, 256, 0, stream>>>(rowptr, col, w, hcur, hn, out);
        hcur = hn;
    }

    k_combine<<<(NC + 255) / 256, 256, 0, stream>>>(x, out, NC);
}

// Round 3
// 929.799 us; speedup vs baseline: 4.0560x; 2.0007x over previous
//
#include <hip/hip_runtime.h>

#define NN 100000
#define NE 1600000
#define CH 64
#define STEPS 10
#define ALPHA 0.1f

#define SCAN_BLK 256
#define SCAN_ITEMS 4
#define SCAN_TILE (SCAN_BLK * SCAN_ITEMS)   // 1024
#define N_TILES ((NN + SCAN_TILE - 1) / SCAN_TILE)  // 98

// ---- histogram of dst ----
__global__ void k_count(const int* __restrict__ dst, int* __restrict__ cnt, int E) {
    int e = blockIdx.x * blockDim.x + threadIdx.x;
    if (e < E) atomicAdd(&cnt[dst[e]], 1);
}

// ---- dinv = rsqrt(max(deg,1)) ----
__global__ void k_dinv(const int* __restrict__ cnt, float* __restrict__ dinv, int n) {
    int i = blockIdx.x * blockDim.x + threadIdx.x;
    if (i < n) dinv[i] = rsqrtf(fmaxf((float)cnt[i], 1.0f));
}

// ---- scan phase 1: per-tile sums ----
__global__ void k_scan1(const int* __restrict__ cnt, int* __restrict__ tileSums, int n) {
    __shared__ int lds[SCAN_BLK];
    int base = blockIdx.x * SCAN_TILE + threadIdx.x * SCAN_ITEMS;
    int s = 0;
    #pragma unroll
    for (int j = 0; j < SCAN_ITEMS; ++j) { int i = base + j; if (i < n) s += cnt[i]; }
    lds[threadIdx.x] = s;
    __syncthreads();
    for (int off = SCAN_BLK / 2; off > 0; off >>= 1) {
        if (threadIdx.x < off) lds[threadIdx.x] += lds[threadIdx.x + off];
        __syncthreads();
    }
    if (threadIdx.x == 0) tileSums[blockIdx.x] = lds[0];
}

// ---- scan phase 2: exclusive scan of tile sums (single small block) ----
__global__ void k_scan2(int* __restrict__ tileSums, int nTiles) {
    __shared__ int lds[256];
    int v = (threadIdx.x < nTiles) ? tileSums[threadIdx.x] : 0;
    lds[threadIdx.x] = v;
    __syncthreads();
    for (int off = 1; off < 256; off <<= 1) {
        int t = (threadIdx.x >= off) ? lds[threadIdx.x - off] : 0;
        __syncthreads();
        lds[threadIdx.x] += t;
        __syncthreads();
    }
    if (threadIdx.x < nTiles) tileSums[threadIdx.x] = lds[threadIdx.x] - v; // exclusive
}

// ---- scan phase 3: per-tile exclusive scan + tile offset -> rowptr & cursor ----
__global__ void k_scan3(const int* __restrict__ cnt, const int* __restrict__ tileOffs,
                        int* __restrict__ rowptr, int* __restrict__ cursor, int n) {
    __shared__ int lds[SCAN_BLK];
    int base = blockIdx.x * SCAN_TILE + threadIdx.x * SCAN_ITEMS;
    int vals[SCAN_ITEMS];
    int s = 0;
    #pragma unroll
    for (int j = 0; j < SCAN_ITEMS; ++j) {
        int i = base + j;
        vals[j] = (i < n) ? cnt[i] : 0;
        s += vals[j];
    }
    lds[threadIdx.x] = s;
    __syncthreads();
    int inc = s;
    for (int off = 1; off < SCAN_BLK; off <<= 1) {
        int t = (threadIdx.x >= off) ? lds[threadIdx.x - off] : 0;
        __syncthreads();
        lds[threadIdx.x] += t;
        __syncthreads();
    }
    int excl = lds[threadIdx.x] - inc + tileOffs[blockIdx.x];
    #pragma unroll
    for (int j = 0; j < SCAN_ITEMS; ++j) {
        int i = base + j;
        if (i < n) { rowptr[i] = excl; cursor[i] = excl; excl += vals[j]; }
    }
    if (blockIdx.x == 0 && threadIdx.x == 0) rowptr[n] = NE;
}

// ---- scatter edges into CSR order (by dst), precompute weight ----
__global__ void k_fill(const int* __restrict__ src, const int* __restrict__ dst,
                       const float* __restrict__ dinv, int* __restrict__ cursor,
                       int* __restrict__ col, float* __restrict__ w, int E) {
    int e = blockIdx.x * blockDim.x + threadIdx.x;
    if (e < E) {
        int s = src[e], d = dst[e];
        int pos = atomicAdd(&cursor[d], 1);
        col[pos] = s;
        w[pos] = dinv[s] * dinv[d];
    }
}

// ---- propagation: one wave per destination node, lane = channel, unroll 4 ----
template<bool INIT, bool WRITEHN, bool FINAL>
__global__ void k_prop(const int* __restrict__ rowptr, const int* __restrict__ col,
                       const float* __restrict__ w, const float* __restrict__ h,
                       float* __restrict__ hn, float* __restrict__ acc,
                       const float* __restrict__ x) {
    int wid  = (int)((blockIdx.x * (long long)blockDim.x + threadIdx.x) >> 6);
    int lane = threadIdx.x & 63;
    if (wid >= NN) return;
    int start = rowptr[wid];
    int end   = rowptr[wid + 1];
    float a = 0.0f;
    int p = start;
    for (; p + 4 <= end; p += 4) {
        int   s0 = col[p],   s1 = col[p+1], s2 = col[p+2], s3 = col[p+3];
        float w0 = w[p],     w1 = w[p+1],   w2 = w[p+2],   w3 = w[p+3];
        float h0 = h[(long long)s0 * CH + lane];
        float h1 = h[(long long)s1 * CH + lane];
        float h2 = h[(long long)s2 * CH + lane];
        float h3 = h[(long long)s3 * CH + lane];
        a = fmaf(h0, w0, a);
        a = fmaf(h1, w1, a);
        a = fmaf(h2, w2, a);
        a = fmaf(h3, w3, a);
    }
    for (; p < end; ++p)
        a = fmaf(h[(long long)col[p] * CH + lane], w[p], a);

    long long o = (long long)wid * CH + lane;
    if (WRITEHN) hn[o] = a;
    if (INIT) {
        acc[o] = a;
    } else if (FINAL) {
        float total = acc[o] + a;
        acc[o] = ALPHA * x[o] + (1.0f - ALPHA) * (total * (1.0f / STEPS));
    } else {
        acc[o] += a;
    }
}

extern "C" void kernel_launch(void* const* d_in, const int* in_sizes, int n_in,
                              void* d_out, int out_size, void* d_ws, size_t ws_size,
                              hipStream_t stream) {
    const float* x  = (const float*)d_in[0];
    const int*   ei = (const int*)d_in[1];     // [2, NE]: row0=src, row1=dst
    const int*   src = ei;
    const int*   dst = ei + NE;
    float* out = (float*)d_out;                // doubles as acc

    char* ws = (char*)d_ws;
    const size_t MB = 1024 * 1024;
    int*   cnt      = (int*)  (ws);                 // 400 KB
    float* dinv     = (float*)(ws + 1 * MB);        // 400 KB
    int*   rowptr   = (int*)  (ws + 2 * MB);        // 400 KB (+1)
    int*   cursor   = (int*)  (ws + 3 * MB);        // 400 KB
    int*   tileSums = (int*)  (ws + 4 * MB);        // <1 KB
    int*   col      = (int*)  (ws + 5 * MB);        // 6.4 MB
    float* w        = (float*)(ws + 12 * MB);       // 6.4 MB
    float* hA       = (float*)(ws + 19 * MB);       // 25.6 MB
    float* hB       = (float*)(ws + 45 * MB);       // 25.6 MB (total ~71 MB)

    hipMemsetAsync(cnt, 0, NN * sizeof(int), stream);
    k_count<<<(NE + 255) / 256, 256, 0, stream>>>(dst, cnt, NE);
    k_dinv <<<(NN + 255) / 256, 256, 0, stream>>>(cnt, dinv, NN);
    k_scan1<<<N_TILES, SCAN_BLK, 0, stream>>>(cnt, tileSums, NN);
    k_scan2<<<1, 256, 0, stream>>>(tileSums, N_TILES);
    k_scan3<<<N_TILES, SCAN_BLK, 0, stream>>>(cnt, tileSums, rowptr, cursor, NN);
    k_fill <<<(NE + 255) / 256, 256, 0, stream>>>(src, dst, dinv, cursor, col, w, NE);

    const int propBlocks = (NN * 64 + 255) / 256;   // one wave per node
    float* bufs[2] = {hA, hB};
    const float* hcur = x;
    for (int t = 0; t < STEPS; ++t) {
        float* hn = bufs[t & 1];
        if (t == 0)
            k_prop<true,  true,  false><<<propBlocks, 256, 0, stream>>>(rowptr, col, w, hcur, hn, out, x);
        else if (t == STEPS - 1)
            k_prop<false, false, true ><<<propBlocks, 256, 0, stream>>>(rowptr, col, w, hcur, hn, out, x);
        else
            k_prop<false, true,  false><<<propBlocks, 256, 0, stream>>>(rowptr, col, w, hcur, hn, out, x);
        hcur = hn;
    }
}

// Round 4
// 896.328 us; speedup vs baseline: 4.2075x; 1.0373x over previous
//
#include <hip/hip_runtime.h>

#define NN 100000
#define NE 1600000
#define CH 64
#define STEPS 10
#define ALPHA 0.1f

#define SCAN_BLK 256
#define SCAN_ITEMS 4
#define SCAN_TILE (SCAN_BLK * SCAN_ITEMS)   // 1024
#define N_TILES ((NN + SCAN_TILE - 1) / SCAN_TILE)  // 98

// ---- histogram of dst ----
__global__ void k_count(const int* __restrict__ dst, int* __restrict__ cnt, int E) {
    int e = blockIdx.x * blockDim.x + threadIdx.x;
    if (e < E) atomicAdd(&cnt[dst[e]], 1);
}

// ---- dinv = rsqrt(max(deg,1)) ----
__global__ void k_dinv(const int* __restrict__ cnt, float* __restrict__ dinv, int n) {
    int i = blockIdx.x * blockDim.x + threadIdx.x;
    if (i < n) dinv[i] = rsqrtf(fmaxf((float)cnt[i], 1.0f));
}

// ---- scan phase 1: per-tile sums ----
__global__ void k_scan1(const int* __restrict__ cnt, int* __restrict__ tileSums, int n) {
    __shared__ int lds[SCAN_BLK];
    int base = blockIdx.x * SCAN_TILE + threadIdx.x * SCAN_ITEMS;
    int s = 0;
    #pragma unroll
    for (int j = 0; j < SCAN_ITEMS; ++j) { int i = base + j; if (i < n) s += cnt[i]; }
    lds[threadIdx.x] = s;
    __syncthreads();
    for (int off = SCAN_BLK / 2; off > 0; off >>= 1) {
        if (threadIdx.x < off) lds[threadIdx.x] += lds[threadIdx.x + off];
        __syncthreads();
    }
    if (threadIdx.x == 0) tileSums[blockIdx.x] = lds[0];
}

// ---- scan phase 2: exclusive scan of tile sums (single small block) ----
__global__ void k_scan2(int* __restrict__ tileSums, int nTiles) {
    __shared__ int lds[256];
    int v = (threadIdx.x < nTiles) ? tileSums[threadIdx.x] : 0;
    lds[threadIdx.x] = v;
    __syncthreads();
    for (int off = 1; off < 256; off <<= 1) {
        int t = (threadIdx.x >= off) ? lds[threadIdx.x - off] : 0;
        __syncthreads();
        lds[threadIdx.x] += t;
        __syncthreads();
    }
    if (threadIdx.x < nTiles) tileSums[threadIdx.x] = lds[threadIdx.x] - v; // exclusive
}

// ---- scan phase 3: per-tile exclusive scan + tile offset -> rowptr & cursor ----
__global__ void k_scan3(const int* __restrict__ cnt, const int* __restrict__ tileOffs,
                        int* __restrict__ rowptr, int* __restrict__ cursor, int n) {
    __shared__ int lds[SCAN_BLK];
    int base = blockIdx.x * SCAN_TILE + threadIdx.x * SCAN_ITEMS;
    int vals[SCAN_ITEMS];
    int s = 0;
    #pragma unroll
    for (int j = 0; j < SCAN_ITEMS; ++j) {
        int i = base + j;
        vals[j] = (i < n) ? cnt[i] : 0;
        s += vals[j];
    }
    lds[threadIdx.x] = s;
    __syncthreads();
    int inc = s;
    for (int off = 1; off < SCAN_BLK; off <<= 1) {
        int t = (threadIdx.x >= off) ? lds[threadIdx.x - off] : 0;
        __syncthreads();
        lds[threadIdx.x] += t;
        __syncthreads();
    }
    int excl = lds[threadIdx.x] - inc + tileOffs[blockIdx.x];
    #pragma unroll
    for (int j = 0; j < SCAN_ITEMS; ++j) {
        int i = base + j;
        if (i < n) { rowptr[i] = excl; cursor[i] = excl; excl += vals[j]; }
    }
    if (blockIdx.x == 0 && threadIdx.x == 0) rowptr[n] = NE;
}

// ---- scatter edges into CSR order (by dst); single packed 8B write per edge ----
__global__ void k_fill(const int* __restrict__ src, const int* __restrict__ dst,
                       const float* __restrict__ dinv, int* __restrict__ cursor,
                       int2* __restrict__ pair, int E) {
    int e = blockIdx.x * blockDim.x + threadIdx.x;
    if (e < E) {
        int s = src[e], d = dst[e];
        int pos = atomicAdd(&cursor[d], 1);
        pair[pos] = make_int2(s, __float_as_int(dinv[s] * dinv[d]));
    }
}

// ---- propagation: one wave per node; 2 edges in flight (one per 32-lane half),
//      lane handles a float2 channel pair; cross-half shfl reduce at the end ----
template<bool INIT, bool WRITEHN, bool FINAL>
__global__ void k_prop(const int* __restrict__ rowptr, const int2* __restrict__ pair,
                       const float* __restrict__ h, float* __restrict__ hn,
                       float* __restrict__ acc, const float* __restrict__ x) {
    int wid  = (int)((blockIdx.x * (long long)blockDim.x + threadIdx.x) >> 6);
    int lane = threadIdx.x & 63;
    if (wid >= NN) return;
    int half = lane >> 5;       // which edge of the pair
    int cl   = lane & 31;       // float2 channel-pair index
    int start = rowptr[wid];
    int end   = rowptr[wid + 1];
    float2 a = make_float2(0.0f, 0.0f);
    int p = start;
    for (; p + 4 <= end; p += 4) {
        int2 c0 = pair[p + half];
        int2 c1 = pair[p + 2 + half];
        float2 h0 = ((const float2*)(h + (long long)c0.x * CH))[cl];
        float2 h1 = ((const float2*)(h + (long long)c1.x * CH))[cl];
        float w0 = __int_as_float(c0.y), w1 = __int_as_float(c1.y);
        a.x = fmaf(h0.x, w0, a.x); a.y = fmaf(h0.y, w0, a.y);
        a.x = fmaf(h1.x, w1, a.x); a.y = fmaf(h1.y, w1, a.y);
    }
    if (p + 2 <= end) {
        int2 c0 = pair[p + half];
        float2 h0 = ((const float2*)(h + (long long)c0.x * CH))[cl];
        float w0 = __int_as_float(c0.y);
        a.x = fmaf(h0.x, w0, a.x); a.y = fmaf(h0.y, w0, a.y);
        p += 2;
    }
    if (p < end && half == 0) {     // odd tail edge: half 0 only
        int2 c0 = pair[p];
        float2 h0 = ((const float2*)(h + (long long)c0.x * CH))[cl];
        float w0 = __int_as_float(c0.y);
        a.x = fmaf(h0.x, w0, a.x); a.y = fmaf(h0.y, w0, a.y);
    }
    a.x += __shfl_xor(a.x, 32);
    a.y += __shfl_xor(a.y, 32);
    if (half == 0) {
        long long o = (long long)wid * (CH / 2) + cl;   // float2 index
        if (WRITEHN) ((float2*)hn)[o] = a;
        if (INIT) {
            ((float2*)acc)[o] = a;
        } else if (FINAL) {
            float2 t = ((float2*)acc)[o];
            t.x += a.x; t.y += a.y;
            float2 xv = ((const float2*)x)[o];
            float2 r;
            r.x = ALPHA * xv.x + (1.0f - ALPHA) * (t.x * (1.0f / STEPS));
            r.y = ALPHA * xv.y + (1.0f - ALPHA) * (t.y * (1.0f / STEPS));
            ((float2*)acc)[o] = r;
        } else {
            float2 t = ((float2*)acc)[o];
            t.x += a.x; t.y += a.y;
            ((float2*)acc)[o] = t;
        }
    }
}

extern "C" void kernel_launch(void* const* d_in, const int* in_sizes, int n_in,
                              void* d_out, int out_size, void* d_ws, size_t ws_size,
                              hipStream_t stream) {
    const float* x  = (const float*)d_in[0];
    const int*   ei = (const int*)d_in[1];     // [2, NE]: row0=src, row1=dst
    const int*   src = ei;
    const int*   dst = ei + NE;
    float* out = (float*)d_out;                // doubles as acc

    char* ws = (char*)d_ws;
    const size_t MB = 1024 * 1024;
    int*   cnt      = (int*)  (ws);                 // 400 KB
    float* dinv     = (float*)(ws + 1 * MB);        // 400 KB
    int*   rowptr   = (int*)  (ws + 2 * MB);        // 400 KB (+1)
    int*   cursor   = (int*)  (ws + 3 * MB);        // 400 KB
    int*   tileSums = (int*)  (ws + 4 * MB);        // <1 KB
    int2*  pair     = (int2*) (ws + 5 * MB);        // 12.8 MB
    float* hA       = (float*)(ws + 19 * MB);       // 25.6 MB
    float* hB       = (float*)(ws + 45 * MB);       // 25.6 MB (total ~71 MB)

    hipMemsetAsync(cnt, 0, NN * sizeof(int), stream);
    k_count<<<(NE + 255) / 256, 256, 0, stream>>>(dst, cnt, NE);
    k_dinv <<<(NN + 255) / 256, 256, 0, stream>>>(cnt, dinv, NN);
    k_scan1<<<N_TILES, SCAN_BLK, 0, stream>>>(cnt, tileSums, NN);
    k_scan2<<<1, 256, 0, stream>>>(tileSums, N_TILES);
    k_scan3<<<N_TILES, SCAN_BLK, 0, stream>>>(cnt, tileSums, rowptr, cursor, NN);
    k_fill <<<(NE + 255) / 256, 256, 0, stream>>>(src, dst, dinv, cursor, pair, NE);

    const int propBlocks = (NN * 64 + 255) / 256;   // one wave per node
    float* bufs[2] = {hA, hB};
    const float* hcur = x;
    for (int t = 0; t < STEPS; ++t) {
        float* hn = bufs[t & 1];
        if (t == 0)
            k_prop<true,  true,  false><<<propBlocks, 256, 0, stream>>>(rowptr, pair, hcur, hn, out, x);
        else if (t == STEPS - 1)
            k_prop<false, false, true ><<<propBlocks, 256, 0, stream>>>(rowptr, pair, hcur, hn, out, x);
        else
            k_prop<false, true,  false><<<propBlocks, 256, 0, stream>>>(rowptr, pair, hcur, hn, out, x);
        hcur = hn;
    }
}

// Round 5
// 803.941 us; speedup vs baseline: 4.6910x; 1.1149x over previous
//
#include <hip/hip_runtime.h>

#define NN 100000
#define NE 1600000
#define CH 64
#define STEPS 10
#define ALPHA 0.1f

#define SCAN_BLK 256
#define SCAN_ITEMS 4
#define SCAN_TILE (SCAN_BLK * SCAN_ITEMS)   // 1024
#define N_TILES ((NN + SCAN_TILE - 1) / SCAN_TILE)  // 98

typedef unsigned int uint;

// pack two f32 into bf16x2 word, round-to-nearest-even
__device__ inline uint pack_bf16x2(float x, float y) {
    uint ux = __float_as_uint(x);
    ux += 0x7FFFu + ((ux >> 16) & 1u);
    uint uy = __float_as_uint(y);
    uy += 0x7FFFu + ((uy >> 16) & 1u);
    return (ux >> 16) | (uy & 0xFFFF0000u);
}

// ---- histogram of dst ----
__global__ void k_count(const int* __restrict__ dst, int* __restrict__ cnt, int E) {
    int e = blockIdx.x * blockDim.x + threadIdx.x;
    if (e < E) atomicAdd(&cnt[dst[e]], 1);
}

// ---- dinv = rsqrt(max(deg,1)) ----
__global__ void k_dinv(const int* __restrict__ cnt, float* __restrict__ dinv, int n) {
    int i = blockIdx.x * blockDim.x + threadIdx.x;
    if (i < n) dinv[i] = rsqrtf(fmaxf((float)cnt[i], 1.0f));
}

// ---- scan phase 1: per-tile sums ----
__global__ void k_scan1(const int* __restrict__ cnt, int* __restrict__ tileSums, int n) {
    __shared__ int lds[SCAN_BLK];
    int base = blockIdx.x * SCAN_TILE + threadIdx.x * SCAN_ITEMS;
    int s = 0;
    #pragma unroll
    for (int j = 0; j < SCAN_ITEMS; ++j) { int i = base + j; if (i < n) s += cnt[i]; }
    lds[threadIdx.x] = s;
    __syncthreads();
    for (int off = SCAN_BLK / 2; off > 0; off >>= 1) {
        if (threadIdx.x < off) lds[threadIdx.x] += lds[threadIdx.x + off];
        __syncthreads();
    }
    if (threadIdx.x == 0) tileSums[blockIdx.x] = lds[0];
}

// ---- scan phase 2: exclusive scan of tile sums ----
__global__ void k_scan2(int* __restrict__ tileSums, int nTiles) {
    __shared__ int lds[256];
    int v = (threadIdx.x < nTiles) ? tileSums[threadIdx.x] : 0;
    lds[threadIdx.x] = v;
    __syncthreads();
    for (int off = 1; off < 256; off <<= 1) {
        int t = (threadIdx.x >= off) ? lds[threadIdx.x - off] : 0;
        __syncthreads();
        lds[threadIdx.x] += t;
        __syncthreads();
    }
    if (threadIdx.x < nTiles) tileSums[threadIdx.x] = lds[threadIdx.x] - v;
}

// ---- scan phase 3: per-tile exclusive scan + tile offset -> rowptr & cursor ----
__global__ void k_scan3(const int* __restrict__ cnt, const int* __restrict__ tileOffs,
                        int* __restrict__ rowptr, int* __restrict__ cursor, int n) {
    __shared__ int lds[SCAN_BLK];
    int base = blockIdx.x * SCAN_TILE + threadIdx.x * SCAN_ITEMS;
    int vals[SCAN_ITEMS];
    int s = 0;
    #pragma unroll
    for (int j = 0; j < SCAN_ITEMS; ++j) {
        int i = base + j;
        vals[j] = (i < n) ? cnt[i] : 0;
        s += vals[j];
    }
    lds[threadIdx.x] = s;
    __syncthreads();
    int inc = s;
    for (int off = 1; off < SCAN_BLK; off <<= 1) {
        int t = (threadIdx.x >= off) ? lds[threadIdx.x - off] : 0;
        __syncthreads();
        lds[threadIdx.x] += t;
        __syncthreads();
    }
    int excl = lds[threadIdx.x] - inc + tileOffs[blockIdx.x];
    #pragma unroll
    for (int j = 0; j < SCAN_ITEMS; ++j) {
        int i = base + j;
        if (i < n) { rowptr[i] = excl; cursor[i] = excl; excl += vals[j]; }
    }
    if (blockIdx.x == 0 && threadIdx.x == 0) rowptr[n] = NE;
}

// ---- scatter edges into CSR order (by dst); single packed 8B write per edge ----
__global__ void k_fill(const int* __restrict__ src, const int* __restrict__ dst,
                       const float* __restrict__ dinv, int* __restrict__ cursor,
                       int2* __restrict__ pair, int E) {
    int e = blockIdx.x * blockDim.x + threadIdx.x;
    if (e < E) {
        int s = src[e], d = dst[e];
        int pos = atomicAdd(&cursor[d], 1);
        pair[pos] = make_int2(s, __float_as_int(dinv[s] * dinv[d]));
    }
}

// ---- propagation: one wave per node; 2 edges in flight (one per 32-lane half),
//      lane owns a channel pair. Intermediate h is bf16x2; acc stays f32. ----
template<bool SRCF32, bool INIT, bool WRITEHN, bool FINAL>
__global__ void k_prop(const int* __restrict__ rowptr, const int2* __restrict__ pair,
                       const void* __restrict__ h, uint* __restrict__ hn,
                       float* __restrict__ acc, const float* __restrict__ x) {
    int wid  = (int)((blockIdx.x * (long long)blockDim.x + threadIdx.x) >> 6);
    int lane = threadIdx.x & 63;
    if (wid >= NN) return;
    int half = lane >> 5;       // which edge of the pair
    int cl   = lane & 31;       // channel-pair index
    int start = rowptr[wid];
    int end   = rowptr[wid + 1];
    float ax = 0.0f, ay = 0.0f;

    #define EDGE_ACC(c)                                                          \
        {                                                                        \
            float wt = __int_as_float((c).y);                                    \
            if (SRCF32) {                                                        \
                float2 hv = ((const float2*)((const float*)h + (long long)(c).x * CH))[cl]; \
                ax = fmaf(hv.x, wt, ax); ay = fmaf(hv.y, wt, ay);                \
            } else {                                                             \
                uint v = ((const uint*)h)[(long long)(c).x * (CH/2) + cl];       \
                ax = fmaf(__uint_as_float(v << 16), wt, ax);                     \
                ay = fmaf(__uint_as_float(v & 0xFFFF0000u), wt, ay);             \
            }                                                                    \
        }

    int p = start;
    for (; p + 4 <= end; p += 4) {
        int2 c0 = pair[p + half];
        int2 c1 = pair[p + 2 + half];
        EDGE_ACC(c0);
        EDGE_ACC(c1);
    }
    if (p + 2 <= end) {
        int2 c0 = pair[p + half];
        EDGE_ACC(c0);
        p += 2;
    }
    if (p < end && half == 0) {
        int2 c0 = pair[p];
        EDGE_ACC(c0);
    }
    #undef EDGE_ACC

    ax += __shfl_xor(ax, 32);
    ay += __shfl_xor(ay, 32);
    if (half == 0) {
        long long o = (long long)wid * (CH / 2) + cl;
        if (WRITEHN) hn[o] = pack_bf16x2(ax, ay);
        if (INIT) {
            ((float2*)acc)[o] = make_float2(ax, ay);
        } else if (FINAL) {
            float2 t = ((float2*)acc)[o];
            t.x += ax; t.y += ay;
            float2 xv = ((const float2*)x)[o];
            float2 r;
            r.x = ALPHA * xv.x + (1.0f - ALPHA) * (t.x * (1.0f / STEPS));
            r.y = ALPHA * xv.y + (1.0f - ALPHA) * (t.y * (1.0f / STEPS));
            ((float2*)acc)[o] = r;
        } else {
            float2 t = ((float2*)acc)[o];
            t.x += ax; t.y += ay;
            ((float2*)acc)[o] = t;
        }
    }
}

extern "C" void kernel_launch(void* const* d_in, const int* in_sizes, int n_in,
                              void* d_out, int out_size, void* d_ws, size_t ws_size,
                              hipStream_t stream) {
    const float* x  = (const float*)d_in[0];
    const int*   ei = (const int*)d_in[1];     // [2, NE]: row0=src, row1=dst
    const int*   src = ei;
    const int*   dst = ei + NE;
    float* out = (float*)d_out;                // doubles as f32 acc

    char* ws = (char*)d_ws;
    const size_t MB = 1024 * 1024;
    int*   cnt      = (int*)  (ws);                 // 400 KB
    float* dinv     = (float*)(ws + 1 * MB);        // 400 KB
    int*   rowptr   = (int*)  (ws + 2 * MB);        // 400 KB (+1)
    int*   cursor   = (int*)  (ws + 3 * MB);        // 400 KB
    int*   tileSums = (int*)  (ws + 4 * MB);        // <1 KB
    int2*  pair     = (int2*) (ws + 5 * MB);        // 12.8 MB
    uint*  hA       = (uint*) (ws + 19 * MB);       // 12.8 MB (bf16x2)
    uint*  hB       = (uint*) (ws + 33 * MB);       // 12.8 MB (total ~46 MB)

    hipMemsetAsync(cnt, 0, NN * sizeof(int), stream);
    k_count<<<(NE + 255) / 256, 256, 0, stream>>>(dst, cnt, NE);
    k_dinv <<<(NN + 255) / 256, 256, 0, stream>>>(cnt, dinv, NN);
    k_scan1<<<N_TILES, SCAN_BLK, 0, stream>>>(cnt, tileSums, NN);
    k_scan2<<<1, 256, 0, stream>>>(tileSums, N_TILES);
    k_scan3<<<N_TILES, SCAN_BLK, 0, stream>>>(cnt, tileSums, rowptr, cursor, NN);
    k_fill <<<(NE + 255) / 256, 256, 0, stream>>>(src, dst, dinv, cursor, pair, NE);

    const int propBlocks = (NN * 64 + 255) / 256;   // one wave per node
    uint* bufs[2] = {hA, hB};
    const void* hcur = (const void*)x;
    for (int t = 0; t < STEPS; ++t) {
        uint* hn = bufs[t & 1];
        if (t == 0)
            k_prop<true,  true,  true,  false><<<propBlocks, 256, 0, stream>>>(rowptr, pair, hcur, hn, out, x);
        else if (t == STEPS - 1)
            k_prop<false, false, false, true ><<<propBlocks, 256, 0, stream>>>(rowptr, pair, hcur, hn, out, x);
        else
            k_prop<false, false, true,  false><<<propBlocks, 256, 0, stream>>>(rowptr, pair, hcur, hn, out, x);
        hcur = (const void*)hn;
    }
}